// Round 5
// baseline (71.453 us; speedup 1.0000x reference)
//
#include <hip/hip_runtime.h>
#include <math.h>

// Tropical max/min-plus pseudo-matmul.
// out[b,u] = max_f(x[b,f] + w[f,u]) for u<128, min_f otherwise.
//
// R17: structural rewrite -- NO LDS in the main loop, NO sign arithmetic.
// R13-R16 post-mortem: the lane-split family never beat R12 (~10.7us kernel).
// Root cause of the R12 plateau: x came from LDS as broadcast b128 reads
// (12cyc each, 16B unique data), and with 2 waves/SIMD the lgkm waits on the
// saturated LDS unit serialized with VALU (R10: 5.5 + 5.1 SUMMING).
// Fix A: x[r][k] is WAVE-UNIFORM -> load it straight from global as a
//   broadcast dwordx4 (1 L1 transaction; 64B lines serve 4 steps; waves 0&4
//   read identical slices -> L1-warm). x is never re-read: 4KB/wave total.
//   LDS is used ONLY for the epilogue combine (one barrier in the kernel).
// Fix B: min/max split by WAVE, not lane: waves 0-3 -> units 0-127 max3,
//   waves 4-7 -> units 128-255 min3. Wave-uniform branch, zero divergence,
//   zero sign-folds, zero epilogue sign-undo. Each wave: k-slice of 128,
//   2 units/lane (w loads: dwordx2, 512B/instr contiguous).
// VALU = 96 inst/step x 32 steps = 3072/wave = the 1.5-inst-per-(k,u) floor
// (~5.1-5.6us across 2 waves/SIMD). w from L2 (~24 TB/s demand, 70% of
// ceiling) and x broadcast loads overlap under the A/B software pipeline.
// VGPR ~120: acc 16 + x 2x32 + w 2x8 + addr. Occupancy belt kept from R15:
// 96KB LDS decl + waves_per_eu(2,2) -> allocator budgets 256 VGPR for the
// real 1-block/CU, 2-wave/SIMD config (32KB real LDS would imply 4 blocks/CU
// -> 64-VGPR budget -> R13-style catastrophic spill).

#define FEAT  512
#define UNITS 256
#define BR    8            // rows per block
#define NW    8            // waves per block
#define KW    128          // k per wave (FEAT / 4 k-slices)
#define NS    (KW / 4)     // 32 steps, 4 k per step
#define LDSZ  24576        // 96KB declared (occupancy belt); 32KB used

__device__ __forceinline__ float max3f(float a, float b, float c) {
    return fmaxf(fmaxf(a, b), c);   // v_max3_f32
}
__device__ __forceinline__ float min3f(float a, float b, float c) {
    return fminf(fminf(a, b), c);   // v_min3_f32
}

// 8 broadcast dwordx4 from global: x[row0+r][ks + s*4 .. +3] (uniform addr)
__device__ __forceinline__ void load_xstep(const float* __restrict__ xp, int s,
                                           float4* __restrict__ xb) {
    #pragma unroll
    for (int r = 0; r < BR; ++r)
        xb[r] = *(const float4*)(xp + r * FEAT + s * 4);
}

// 4 dwordx2: w[ks+s*4+j][u0..u0+1] -- 64 lanes x 8B = 512B contiguous
__device__ __forceinline__ void load_wstep(const float* __restrict__ wp, int s,
                                           float2* __restrict__ wb) {
    #pragma unroll
    for (int j = 0; j < 4; ++j)
        wb[j] = *(const float2*)(wp + (size_t)(s * 4 + j) * UNITS);
}

// per step: 8 rows x (8 add + 4 max3/min3) = 96 VALU inst
template<bool ISMAX>
__device__ __forceinline__ void compute_step(const float4* __restrict__ xb,
                                             const float2* __restrict__ wq,
                                             float2* __restrict__ acc) {
    #pragma unroll
    for (int r = 0; r < BR; ++r) {
        const float4 a = xb[r];
        const float t0x = a.x + wq[0].x, t0y = a.x + wq[0].y;
        const float t1x = a.y + wq[1].x, t1y = a.y + wq[1].y;
        const float t2x = a.z + wq[2].x, t2y = a.z + wq[2].y;
        const float t3x = a.w + wq[3].x, t3y = a.w + wq[3].y;
        float2 A = acc[r];
        if (ISMAX) {
            A.x = max3f(A.x, t0x, t1x);  A.x = max3f(A.x, t2x, t3x);
            A.y = max3f(A.y, t0y, t1y);  A.y = max3f(A.y, t2y, t3y);
        } else {
            A.x = min3f(A.x, t0x, t1x);  A.x = min3f(A.x, t2x, t3x);
            A.y = min3f(A.y, t0y, t1y);  A.y = min3f(A.y, t2y, t3y);
        }
        acc[r] = A;
    }
}

// A/B software pipeline: both operand sets loaded one step ahead
template<bool ISMAX>
__device__ __forceinline__ void main_loop(const float* __restrict__ xp,
                                          const float* __restrict__ wp,
                                          float2* __restrict__ acc) {
    float4 xA[BR], xB[BR];
    float2 wA[4], wB[4];
    load_xstep(xp, 0, xA);
    load_wstep(wp, 0, wA);
    #pragma unroll 1
    for (int s = 0; s < NS; s += 2) {
        load_xstep(xp, s + 1, xB);
        load_wstep(wp, s + 1, wB);
        compute_step<ISMAX>(xA, wA, acc);     // covers the B-loads
        if (s + 2 < NS) {
            load_xstep(xp, s + 2, xA);
            load_wstep(wp, s + 2, wA);
        }
        compute_step<ISMAX>(xB, wB, acc);     // covers the A-loads
    }
}

__global__ __launch_bounds__(512)
__attribute__((amdgpu_waves_per_eu(2, 2)))
void tropical_kernel(const float* __restrict__ x,
                     const float* __restrict__ w,
                     float* __restrict__ out) {
    __shared__ float lds[LDSZ];   // 96KB declared (belt); first 32KB used
    const int tid  = threadIdx.x;
    const int lane = tid & 63;
    const int wv   = __builtin_amdgcn_readfirstlane(tid >> 6);  // 0..7
    const int ks   = (wv & 3) * KW;      // this wave's k origin (0/128/256/384)
    const int half = wv >> 2;            // 0: max units 0-127, 1: min units 128-255
    const int u0   = lane * 2;           // 2 units per lane, contiguous
    const int row0 = blockIdx.x * BR;

    const float* xp = x + (size_t)row0 * FEAT + ks;
    const float* wp = w + (size_t)ks * UNITS + half * 128 + u0;

    float2 acc[BR];
    const float init = half ? __builtin_inff() : -__builtin_inff();
    #pragma unroll
    for (int r = 0; r < BR; ++r)
        acc[r] = make_float2(init, init);

    if (half == 0) main_loop<true >(xp, wp, acc);
    else           main_loop<false>(xp, wp, acc);

    // ---- partials to LDS: wave wv, rows r, 128 units of its half ----
    #pragma unroll
    for (int r = 0; r < BR; ++r)
        *(float2*)&lds[(wv * BR + r) * 128 + u0] = acc[r];   // 512B/wave-row
    __syncthreads();   // the kernel's only barrier

    // ---- combine 4 k-slice partials; thread -> float4 of output ----
    const int r  = tid >> 6;            // 0..7
    const int u4 = (tid & 63) * 4;      // lanes<32: max half, >=32: min half
    const int hh = u4 >> 7;             // 0/1
    const int uo = u4 & 127;
    const float4 p0 = *(const float4*)&lds[((hh * 4 + 0) * BR + r) * 128 + uo];
    const float4 p1 = *(const float4*)&lds[((hh * 4 + 1) * BR + r) * 128 + uo];
    const float4 p2 = *(const float4*)&lds[((hh * 4 + 2) * BR + r) * 128 + uo];
    const float4 p3 = *(const float4*)&lds[((hh * 4 + 3) * BR + r) * 128 + uo];
    float4 v;
    if (hh == 0) {
        v.x = fmaxf(fmaxf(p0.x, p1.x), fmaxf(p2.x, p3.x));
        v.y = fmaxf(fmaxf(p0.y, p1.y), fmaxf(p2.y, p3.y));
        v.z = fmaxf(fmaxf(p0.z, p1.z), fmaxf(p2.z, p3.z));
        v.w = fmaxf(fmaxf(p0.w, p1.w), fmaxf(p2.w, p3.w));
    } else {
        v.x = fminf(fminf(p0.x, p1.x), fminf(p2.x, p3.x));
        v.y = fminf(fminf(p0.y, p1.y), fminf(p2.y, p3.y));
        v.z = fminf(fminf(p0.z, p1.z), fminf(p2.z, p3.z));
        v.w = fminf(fminf(p0.w, p1.w), fminf(p2.w, p3.w));
    }
    *(float4*)&out[(size_t)(row0 + r) * UNITS + u4] = v;
}

extern "C" void kernel_launch(void* const* d_in, const int* in_sizes, int n_in,
                              void* d_out, int out_size, void* d_ws, size_t ws_size,
                              hipStream_t stream) {
    const float* x = (const float*)d_in[0];   // (2048, 512)
    const float* w = (const float*)d_in[1];   // (512, 256)
    float* out = (float*)d_out;               // (2048, 256)

    // 256 blocks x 8 waves = 2048 waves = 2/SIMD, 1 block/CU
    tropical_kernel<<<dim3(2048 / BR), dim3(512), 0, stream>>>(x, w, out);
}

// Round 7
// 68.065 us; speedup vs baseline: 1.0498x; 1.0498x over previous
//
#include <hip/hip_runtime.h>
#include <math.h>

// Tropical max/min-plus pseudo-matmul.
// out[b,u] = max_f(x[b,f] + w[f,u]) for u<128, min_f otherwise.
//
// R19 = R18 with the host-pass compile fix.
// R18 failed host compile: float4::operator= (HIP_vector_type) cannot bind
// its const& parameter to an address-space(4) object. Fundamental types are
// fine -- so load x as 4 scalar floats through the AS4 pointer; the AMDGPU
// load/store optimizer merges adjacent uniform s_load_dword into
// s_load_dwordx4 (same pass that merges kernel-arg loads). Theory unchanged:
//
// x through the SCALAR pipe (s_load/SGPR), not a 64-lane broadcast.
// R17 post-mortem: broadcast 16B global loads cost the same ~1KB regfile
// writeback as LDS broadcasts; per CU 3072 VMEM instr x ~4cyc = 12.3K cyc
// == VALU 12.3K cyc -> two co-saturated pipes, phase-locked at TLP=2 ->
// partial serialization (the R10 disease, relocated). Every x value is
// wave-uniform, so the ONLY free path is SMEM: s_load writes 16B to the
// scalar RF once, VALU reads the SGPR operand directly (v_add v,s,v).
// x pointer lives in the CONSTANT address space (AS4) with fully-uniform
// indices (blockIdx, readfirstlane'd wv, unrolled r/s) -> s_load with imm
// offsets. VMEM is then w-only: 1024 instr/CU ~ 1.7us, far under the
// 12.3Kcyc/SIMD VALU floor (~5.1us). SMEM: 2048 s_loads/CU on the
// otherwise-idle scalar pipe.
// TLP 2->4 waves/SIMD (1024-thr blocks, 16 waves = 8 k-slices x 2 halves,
// KW=64; same 256-block grid, same w traffic). x-in-SGPR drops VGPR need
// to ~55, so waves_per_eu(4,4)'s 128-VGPR budget fits with slack.
// Occupancy belt kept: 96KB LDS decl -> 1 block/CU (real use 64KB epilogue).
// min/max split by WAVE (waves 0-7 max3, 8-15 min3): no divergence, no
// sign arithmetic anywhere.

#define FEAT  512
#define UNITS 256
#define BR    8            // rows per block
#define NW    16           // waves per block (8 k-slices x 2 halves)
#define KW    64           // k per wave
#define NS    (KW / 4)     // 16 steps, 4 k per step
#define LDSZ  24576        // 96KB declared (occupancy belt); 64KB used

typedef __attribute__((address_space(4))) const float cfloat;

__device__ __forceinline__ float max3f(float a, float b, float c) {
    return fmaxf(fmaxf(a, b), c);   // v_max3_f32
}
__device__ __forceinline__ float min3f(float a, float b, float c) {
    return fminf(fminf(a, b), c);   // v_min3_f32
}

// 8 x s_load_dwordx4 (after merge): x[row0+r][ks + s*4 .. +3], imm offsets
__device__ __forceinline__ void load_xstep(cfloat* __restrict__ xp, int s,
                                           float4* __restrict__ xb) {
    #pragma unroll
    for (int r = 0; r < BR; ++r) {
        const int o = r * FEAT + s * 4;
        xb[r].x = xp[o + 0];     // scalar copies: no operator= AS issue
        xb[r].y = xp[o + 1];
        xb[r].z = xp[o + 2];
        xb[r].w = xp[o + 3];
    }
}

// 4 dwordx2: w[ks+s*4+j][u0..u0+1] -- 64 lanes x 8B = 512B contiguous
__device__ __forceinline__ void load_wstep(const float* __restrict__ wp, int s,
                                           float2* __restrict__ wb) {
    #pragma unroll
    for (int j = 0; j < 4; ++j)
        wb[j] = *(const float2*)(wp + (size_t)(s * 4 + j) * UNITS);
}

// per step: 8 rows x (8 add + 4 max3/min3) = 96 VALU inst; x from SGPRs
template<bool ISMAX>
__device__ __forceinline__ void compute_step(const float4* __restrict__ xb,
                                             const float2* __restrict__ wq,
                                             float2* __restrict__ acc) {
    #pragma unroll
    for (int r = 0; r < BR; ++r) {
        const float4 a = xb[r];
        const float t0x = a.x + wq[0].x, t0y = a.x + wq[0].y;
        const float t1x = a.y + wq[1].x, t1y = a.y + wq[1].y;
        const float t2x = a.z + wq[2].x, t2y = a.z + wq[2].y;
        const float t3x = a.w + wq[3].x, t3y = a.w + wq[3].y;
        float2 A = acc[r];
        if (ISMAX) {
            A.x = max3f(A.x, t0x, t1x);  A.x = max3f(A.x, t2x, t3x);
            A.y = max3f(A.y, t0y, t1y);  A.y = max3f(A.y, t2y, t3y);
        } else {
            A.x = min3f(A.x, t0x, t1x);  A.x = min3f(A.x, t2x, t3x);
            A.y = min3f(A.y, t0y, t1y);  A.y = min3f(A.y, t2y, t3y);
        }
        acc[r] = A;
    }
}

// A/B software pipeline: both operand sets loaded one step ahead
template<bool ISMAX>
__device__ __forceinline__ void main_loop(cfloat* __restrict__ xp,
                                          const float* __restrict__ wp,
                                          float2* __restrict__ acc) {
    float4 xA[BR], xB[BR];
    float2 wA[4], wB[4];
    load_xstep(xp, 0, xA);
    load_wstep(wp, 0, wA);
    #pragma unroll 1
    for (int s = 0; s < NS; s += 2) {
        load_xstep(xp, s + 1, xB);
        load_wstep(wp, s + 1, wB);
        compute_step<ISMAX>(xA, wA, acc);     // covers the B-loads
        if (s + 2 < NS) {
            load_xstep(xp, s + 2, xA);
            load_wstep(wp, s + 2, wA);
        }
        compute_step<ISMAX>(xB, wB, acc);     // covers the A-loads
    }
}

__global__ __launch_bounds__(1024)
__attribute__((amdgpu_waves_per_eu(4, 4)))
void tropical_kernel(const float* __restrict__ x,
                     const float* __restrict__ w,
                     float* __restrict__ out) {
    __shared__ float lds[LDSZ];   // 96KB declared (belt); 64KB used
    const int tid  = threadIdx.x;
    const int lane = tid & 63;
    const int wv   = __builtin_amdgcn_readfirstlane(tid >> 6);  // 0..15
    const int kslice = wv & 7;           // k origin index
    const int half   = wv >> 3;          // 0: max units 0-127, 1: min 128-255
    const int ks   = kslice * KW;
    const int u0   = lane * 2;           // 2 units per lane, contiguous
    const int row0 = blockIdx.x * BR;

    // x pointer in the CONSTANT address space -> uniform loads become s_load
    cfloat* xp = (cfloat*)(unsigned long long)(x + (size_t)row0 * FEAT + ks);
    const float* wp = w + (size_t)ks * UNITS + half * 128 + u0;

    float2 acc[BR];
    const float init = half ? __builtin_inff() : -__builtin_inff();
    #pragma unroll
    for (int r = 0; r < BR; ++r)
        acc[r] = make_float2(init, init);

    if (half == 0) main_loop<true >(xp, wp, acc);
    else           main_loop<false>(xp, wp, acc);

    // ---- partials to LDS: wave wv -> slot wv, 128 units of its half ----
    #pragma unroll
    for (int r = 0; r < BR; ++r)
        *(float2*)&lds[(wv * BR + r) * 128 + u0] = acc[r];   // 512B/wave-row
    __syncthreads();   // the kernel's only barrier

    // ---- combine 8 k-slice partials; thread -> float2 of output ----
    const int r  = tid >> 7;             // 0..7
    const int j2 = tid & 127;
    const int hh = j2 >> 6;              // wave-uniform: 0=max half, 1=min half
    const int uo = (j2 & 63) * 2;        // unit offset within the half
    float2 v = *(const float2*)&lds[((hh * 8 + 0) * BR + r) * 128 + uo];
    #pragma unroll
    for (int j = 1; j < 8; ++j) {
        const float2 p = *(const float2*)&lds[((hh * 8 + j) * BR + r) * 128 + uo];
        if (hh == 0) { v.x = fmaxf(v.x, p.x); v.y = fmaxf(v.y, p.y); }
        else         { v.x = fminf(v.x, p.x); v.y = fminf(v.y, p.y); }
    }
    *(float2*)&out[(size_t)(row0 + r) * UNITS + hh * 128 + uo] = v;
}

extern "C" void kernel_launch(void* const* d_in, const int* in_sizes, int n_in,
                              void* d_out, int out_size, void* d_ws, size_t ws_size,
                              hipStream_t stream) {
    const float* x = (const float*)d_in[0];   // (2048, 512)
    const float* w = (const float*)d_in[1];   // (512, 256)
    float* out = (float*)d_out;               // (2048, 256)

    // 256 blocks x 16 waves = 1 block/CU, 4 waves/SIMD
    tropical_kernel<<<dim3(2048 / BR), dim3(1024), 0, stream>>>(x, w, out);
}